// Round 1
// baseline (285.592 us; speedup 1.0000x reference)
//
#include <hip/hip_runtime.h>
#include <hip/hip_bf16.h>
#include <math.h>

#define BB 4
#define NN 512
#define DD 64
#define HH 8
#define DKK 8

// ---------------- Kernel 1: QKV projection ----------------
// Q,K,V layout: [B][N][64] with d = h*8+dk (h-major), same as n @ W natural output.
__global__ __launch_bounds__(64) void qkv_kernel(
    const float* __restrict__ n,
    const float* __restrict__ Wq,
    const float* __restrict__ Wk,
    const float* __restrict__ Wv,
    float* __restrict__ Q,
    float* __restrict__ K,
    float* __restrict__ V)
{
    const int row = blockIdx.x;        // b*N + i
    const int j = threadIdx.x;         // 0..63
    __shared__ __align__(16) float nr[DD];
    nr[j] = n[(size_t)row * DD + j];
    __syncthreads();
    float q = 0.f, k = 0.f, v = 0.f;
#pragma unroll
    for (int d = 0; d < DD; ++d) {
        const float nv = nr[d];
        q = fmaf(nv, Wq[d * DD + j], q);
        k = fmaf(nv, Wk[d * DD + j], k);
        v = fmaf(nv, Wv[d * DD + j], v);
    }
    Q[(size_t)row * DD + j] = q;
    K[(size_t)row * DD + j] = k;
    V[(size_t)row * DD + j] = v;
}

// ---------------- Kernel 2: fused edge + attention ----------------
// One block of 256 threads per (b, i). Thread t handles m = t and m = t+256.
__global__ __launch_bounds__(256) void attn_kernel(
    const float* __restrict__ e,
    const float* __restrict__ Q,
    const float* __restrict__ K,
    const float* __restrict__ V,
    const float* __restrict__ We,   // [64][8]
    const float* __restrict__ Wg,   // [64][8]
    const float* __restrict__ Oe,   // [8][64]
    const float* __restrict__ On,   // [64][64]
    float* __restrict__ n_out,      // [B][N][64]
    float* __restrict__ e_out)      // [B][N][N][64]
{
    const int row = blockIdx.x;        // b*N + i
    const int b = row >> 9;            // row / 512
    const int t = threadIdx.x;
    const int lane = t & 63;
    const int wv = t >> 6;             // wave id 0..3

    __shared__ __align__(16) float q_lds[DD];
    __shared__ float eb_lds[HH][NN];   // 16 KB
    __shared__ float gpart[4][HH];
    __shared__ float gsum[HH];
    __shared__ float vh_lds[DD];

    if (t < DD) q_lds[t] = Q[(size_t)row * DD + t];
    __syncthreads();

    const float scale = 0.35355339059327373f;  // 1/sqrt(8)

    float gs[HH];
#pragma unroll
    for (int h = 0; h < HH; ++h) gs[h] = 0.f;

    const float* __restrict__ e_row_base = e + (size_t)row * NN * DD;
    float* __restrict__ eo_base = e_out + (size_t)row * NN * DD;
    const float* __restrict__ Kb = K + (size_t)b * NN * DD;

    for (int mm = 0; mm < 2; ++mm) {
        const int m = t + mm * 256;
        const float4* __restrict__ er = (const float4*)(e_row_base + (size_t)m * DD);
        const float4* __restrict__ kr = (const float4*)(Kb + (size_t)m * DD);

        float ea[HH], ga[HH], aa[HH];
#pragma unroll
        for (int h = 0; h < HH; ++h) { ea[h] = 0.f; ga[h] = 0.f; aa[h] = 0.f; }

#pragma unroll
        for (int c = 0; c < DD / 4; ++c) {     // 16 float4 chunks
            const float4 ev = er[c];
            const float4 kv = kr[c];
            const float4 qv = *(const float4*)&q_lds[c * 4];
            // head index for this chunk's K-dot: d in [4c,4c+3], head = 4c/8 = c/2 (constant)
            const int ha = c >> 1;
            aa[ha] = fmaf(qv.x, kv.x, aa[ha]);
            aa[ha] = fmaf(qv.y, kv.y, aa[ha]);
            aa[ha] = fmaf(qv.z, kv.z, aa[ha]);
            aa[ha] = fmaf(qv.w, kv.w, aa[ha]);
            const float evs[4] = {ev.x, ev.y, ev.z, ev.w};
#pragma unroll
            for (int j = 0; j < 4; ++j) {
                const int d = c * 4 + j;
                const float evj = evs[j];
#pragma unroll
                for (int h = 0; h < HH; ++h) {
                    ea[h] = fmaf(evj, We[d * HH + h], ea[h]);
                    ga[h] = fmaf(evj, Wg[d * HH + h], ga[h]);
                }
            }
        }

        float eb[HH];
#pragma unroll
        for (int h = 0; h < HH; ++h) {
            float a = aa[h] * scale;
            a = fminf(fmaxf(a, -5.f), 5.f);
            const float ebv = a + ea[h];
            eb[h] = ebv;
            eb_lds[h][m] = ebv;
            gs[h] += 1.f / (1.f + expf(-ga[h]));
        }

        // e_out[b,i,m,:] = sum_h eb[h] * Oe[h][:]
        float4* __restrict__ eo = (float4*)(eo_base + (size_t)m * DD);
#pragma unroll
        for (int c = 0; c < DD / 4; ++c) {
            float4 acc;
            acc.x = 0.f; acc.y = 0.f; acc.z = 0.f; acc.w = 0.f;
#pragma unroll
            for (int h = 0; h < HH; ++h) {
                const float4 ov = *(const float4*)&Oe[h * DD + c * 4];
                const float ebh = eb[h];
                acc.x = fmaf(ebh, ov.x, acc.x);
                acc.y = fmaf(ebh, ov.y, acc.y);
                acc.z = fmaf(ebh, ov.z, acc.z);
                acc.w = fmaf(ebh, ov.w, acc.w);
            }
            eo[c] = acc;
        }
    }

    // ---- deterministic G-sum reduction ----
#pragma unroll
    for (int h = 0; h < HH; ++h) {
        float x = gs[h];
        x += __shfl_xor(x, 1, 64);
        x += __shfl_xor(x, 2, 64);
        x += __shfl_xor(x, 4, 64);
        x += __shfl_xor(x, 8, 64);
        x += __shfl_xor(x, 16, 64);
        x += __shfl_xor(x, 32, 64);
        if (lane == 0) gpart[wv][h] = x;
    }
    __syncthreads();
    if (t < HH) gsum[t] = gpart[0][t] + gpart[1][t] + gpart[2][t] + gpart[3][t];
    __syncthreads();

    // ---- softmax + PV: wave wv handles h = wv and wv+4 ----
    const float* __restrict__ Vb = V + (size_t)b * NN * DD;
#pragma unroll
    for (int hh = 0; hh < 2; ++hh) {
        const int h = wv + hh * 4;
        float x[8];
#pragma unroll
        for (int k = 0; k < 8; ++k) x[k] = eb_lds[h][lane + (k << 6)];
        float mx = x[0];
#pragma unroll
        for (int k = 1; k < 8; ++k) mx = fmaxf(mx, x[k]);
        mx = fmaxf(mx, __shfl_xor(mx, 1, 64));
        mx = fmaxf(mx, __shfl_xor(mx, 2, 64));
        mx = fmaxf(mx, __shfl_xor(mx, 4, 64));
        mx = fmaxf(mx, __shfl_xor(mx, 8, 64));
        mx = fmaxf(mx, __shfl_xor(mx, 16, 64));
        mx = fmaxf(mx, __shfl_xor(mx, 32, 64));
        float p[8];
        float s = 0.f;
#pragma unroll
        for (int k = 0; k < 8; ++k) { p[k] = expf(x[k] - mx); s += p[k]; }
        s += __shfl_xor(s, 1, 64);
        s += __shfl_xor(s, 2, 64);
        s += __shfl_xor(s, 4, 64);
        s += __shfl_xor(s, 8, 64);
        s += __shfl_xor(s, 16, 64);
        s += __shfl_xor(s, 32, 64);

        float pv[8];
#pragma unroll
        for (int dk = 0; dk < 8; ++dk) pv[dk] = 0.f;
#pragma unroll
        for (int k = 0; k < 8; ++k) {
            const float* vr = Vb + (size_t)(lane + (k << 6)) * DD + h * DKK;
            const float4 va = *(const float4*)vr;
            const float4 vb2 = *(const float4*)(vr + 4);
            const float pk = p[k];
            pv[0] = fmaf(pk, va.x, pv[0]);
            pv[1] = fmaf(pk, va.y, pv[1]);
            pv[2] = fmaf(pk, va.z, pv[2]);
            pv[3] = fmaf(pk, va.w, pv[3]);
            pv[4] = fmaf(pk, vb2.x, pv[4]);
            pv[5] = fmaf(pk, vb2.y, pv[5]);
            pv[6] = fmaf(pk, vb2.z, pv[6]);
            pv[7] = fmaf(pk, vb2.w, pv[7]);
        }
#pragma unroll
        for (int dk = 0; dk < 8; ++dk) {
            float x2 = pv[dk];
            x2 += __shfl_xor(x2, 1, 64);
            x2 += __shfl_xor(x2, 2, 64);
            x2 += __shfl_xor(x2, 4, 64);
            x2 += __shfl_xor(x2, 8, 64);
            x2 += __shfl_xor(x2, 16, 64);
            x2 += __shfl_xor(x2, 32, 64);
            pv[dk] = x2;
        }
        if (lane == 0) {
            const float sc = log1pf(gsum[h]) / s;
#pragma unroll
            for (int dk = 0; dk < 8; ++dk) vh_lds[h * DKK + dk] = pv[dk] * sc;
        }
    }
    __syncthreads();

    // ---- n_out[b,i,:] = vh @ On ----
    if (t < DD) {
        const int j = t;
        float acc = 0.f;
#pragma unroll
        for (int d = 0; d < DD; ++d) acc = fmaf(vh_lds[d], On[d * DD + j], acc);
        n_out[(size_t)row * DD + j] = acc;
    }
}

extern "C" void kernel_launch(void* const* d_in, const int* in_sizes, int n_in,
                              void* d_out, int out_size, void* d_ws, size_t ws_size,
                              hipStream_t stream) {
    const float* n  = (const float*)d_in[0];
    const float* e  = (const float*)d_in[1];
    const float* Wq = (const float*)d_in[2];
    const float* Wk = (const float*)d_in[3];
    const float* Wv = (const float*)d_in[4];
    const float* On = (const float*)d_in[5];
    const float* We = (const float*)d_in[6];
    const float* Wg = (const float*)d_in[7];
    const float* Oe = (const float*)d_in[8];

    float* out = (float*)d_out;
    float* n_out = out;                                  // B*N*D floats
    float* e_out = out + (size_t)BB * NN * DD;           // B*N*N*D floats

    float* Q = (float*)d_ws;
    float* K = Q + (size_t)BB * NN * DD;
    float* V = K + (size_t)BB * NN * DD;

    qkv_kernel<<<BB * NN, 64, 0, stream>>>(n, Wq, Wk, Wv, Q, K, V);
    attn_kernel<<<BB * NN, 256, 0, stream>>>(e, Q, K, V, We, Wg, Oe, On, n_out, e_out);
}

// Round 2
// 284.594 us; speedup vs baseline: 1.0035x; 1.0035x over previous
//
#include <hip/hip_runtime.h>
#include <hip/hip_bf16.h>
#include <math.h>

#define BB 4
#define NN 512
#define DD 64
#define HH 8
#define DKK 8

// ---------------- Kernel 1: QKV projection ----------------
__global__ __launch_bounds__(64) void qkv_kernel(
    const float* __restrict__ n,
    const float* __restrict__ Wq,
    const float* __restrict__ Wk,
    const float* __restrict__ Wv,
    float* __restrict__ Q,
    float* __restrict__ K,
    float* __restrict__ V)
{
    const int row = blockIdx.x;        // b*N + i
    const int j = threadIdx.x;         // 0..63
    __shared__ __align__(16) float nr[DD];
    nr[j] = n[(size_t)row * DD + j];
    __syncthreads();
    float q = 0.f, k = 0.f, v = 0.f;
#pragma unroll
    for (int d = 0; d < DD; ++d) {
        const float nv = nr[d];
        q = fmaf(nv, Wq[d * DD + j], q);
        k = fmaf(nv, Wk[d * DD + j], k);
        v = fmaf(nv, Wv[d * DD + j], v);
    }
    Q[(size_t)row * DD + j] = q;
    K[(size_t)row * DD + j] = k;
    V[(size_t)row * DD + j] = v;
}

// ---------------- Kernel 2: fused edge + attention ----------------
// One block of 256 threads per (b, i). Thread t handles m = t and m = t+256.
// Weights We/Wg/Oe staged in LDS, read via uniform-address float4 broadcasts.
__global__ __launch_bounds__(256) void attn_kernel(
    const float* __restrict__ e,
    const float* __restrict__ Q,
    const float* __restrict__ K,
    const float* __restrict__ V,
    const float* __restrict__ We,   // [64][8]
    const float* __restrict__ Wg,   // [64][8]
    const float* __restrict__ Oe,   // [8][64]
    const float* __restrict__ On,   // [64][64]
    float* __restrict__ n_out,      // [B][N][64]
    float* __restrict__ e_out)      // [B][N][N][64]
{
    const int row = blockIdx.x;        // b*N + i
    const int b = row >> 9;            // row / 512
    const int t = threadIdx.x;
    const int lane = t & 63;
    const int wv = t >> 6;             // wave id 0..3

    __shared__ __align__(16) float we_l[DD * HH];   // 512
    __shared__ __align__(16) float wg_l[DD * HH];   // 512
    __shared__ __align__(16) float oe_l[HH * DD];   // 512
    __shared__ __align__(16) float q_lds[DD];
    __shared__ float eb_lds[HH][NN];   // 16 KB
    __shared__ float gpart[4][HH];
    __shared__ float gsum[HH];
    __shared__ float vh_lds[DD];

    // stage weights (6 KB) once per block
#pragma unroll
    for (int idx = t; idx < DD * HH; idx += 256) {
        we_l[idx] = We[idx];
        wg_l[idx] = Wg[idx];
        oe_l[idx] = Oe[idx];
    }
    if (t < DD) q_lds[t] = Q[(size_t)row * DD + t];
    __syncthreads();

    const float scale = 0.35355339059327373f;  // 1/sqrt(8)

    float gs[HH];
#pragma unroll
    for (int h = 0; h < HH; ++h) gs[h] = 0.f;

    const float* __restrict__ e_row_base = e + (size_t)row * NN * DD;
    float* __restrict__ eo_base = e_out + (size_t)row * NN * DD;
    const float* __restrict__ Kb = K + (size_t)b * NN * DD;

    for (int mm = 0; mm < 2; ++mm) {
        const int m = t + mm * 256;
        const float4* __restrict__ er = (const float4*)(e_row_base + (size_t)m * DD);
        const float4* __restrict__ kr = (const float4*)(Kb + (size_t)m * DD);

        float ea[HH], ga[HH], aa[HH];
#pragma unroll
        for (int h = 0; h < HH; ++h) { ea[h] = 0.f; ga[h] = 0.f; aa[h] = 0.f; }

#pragma unroll
        for (int c = 0; c < DD / 4; ++c) {     // 16 float4 chunks
            const float4 ev = er[c];
            const float4 kv = kr[c];
            const float4 qv = *(const float4*)&q_lds[c * 4];
            const int ha = c >> 1;             // head for this chunk (compile-time)
            aa[ha] = fmaf(qv.x, kv.x, aa[ha]);
            aa[ha] = fmaf(qv.y, kv.y, aa[ha]);
            aa[ha] = fmaf(qv.z, kv.z, aa[ha]);
            aa[ha] = fmaf(qv.w, kv.w, aa[ha]);
#pragma unroll
            for (int j = 0; j < 4; ++j) {
                const int d = c * 4 + j;
                const float evj = (j == 0) ? ev.x : (j == 1) ? ev.y : (j == 2) ? ev.z : ev.w;
                // LDS broadcast reads: uniform address across the wave
                const float4 wea = *(const float4*)&we_l[d * HH];
                const float4 web = *(const float4*)&we_l[d * HH + 4];
                const float4 wga = *(const float4*)&wg_l[d * HH];
                const float4 wgb = *(const float4*)&wg_l[d * HH + 4];
                ea[0] = fmaf(evj, wea.x, ea[0]);
                ea[1] = fmaf(evj, wea.y, ea[1]);
                ea[2] = fmaf(evj, wea.z, ea[2]);
                ea[3] = fmaf(evj, wea.w, ea[3]);
                ea[4] = fmaf(evj, web.x, ea[4]);
                ea[5] = fmaf(evj, web.y, ea[5]);
                ea[6] = fmaf(evj, web.z, ea[6]);
                ea[7] = fmaf(evj, web.w, ea[7]);
                ga[0] = fmaf(evj, wga.x, ga[0]);
                ga[1] = fmaf(evj, wga.y, ga[1]);
                ga[2] = fmaf(evj, wga.z, ga[2]);
                ga[3] = fmaf(evj, wga.w, ga[3]);
                ga[4] = fmaf(evj, wgb.x, ga[4]);
                ga[5] = fmaf(evj, wgb.y, ga[5]);
                ga[6] = fmaf(evj, wgb.z, ga[6]);
                ga[7] = fmaf(evj, wgb.w, ga[7]);
            }
        }

        float eb[HH];
#pragma unroll
        for (int h = 0; h < HH; ++h) {
            float a = aa[h] * scale;
            a = fminf(fmaxf(a, -5.f), 5.f);
            const float ebv = a + ea[h];
            eb[h] = ebv;
            eb_lds[h][m] = ebv;
            gs[h] += 1.f / (1.f + expf(-ga[h]));
        }

        // e_out[b,i,m,:] = sum_h eb[h] * Oe[h][:]  (Oe from LDS broadcast)
        float4* __restrict__ eo = (float4*)(eo_base + (size_t)m * DD);
#pragma unroll
        for (int c = 0; c < DD / 4; ++c) {
            float4 acc;
            acc.x = 0.f; acc.y = 0.f; acc.z = 0.f; acc.w = 0.f;
#pragma unroll
            for (int h = 0; h < HH; ++h) {
                const float4 ov = *(const float4*)&oe_l[h * DD + c * 4];
                const float ebh = eb[h];
                acc.x = fmaf(ebh, ov.x, acc.x);
                acc.y = fmaf(ebh, ov.y, acc.y);
                acc.z = fmaf(ebh, ov.z, acc.z);
                acc.w = fmaf(ebh, ov.w, acc.w);
            }
            eo[c] = acc;
        }
    }

    // ---- deterministic G-sum reduction ----
#pragma unroll
    for (int h = 0; h < HH; ++h) {
        float x = gs[h];
        x += __shfl_xor(x, 1, 64);
        x += __shfl_xor(x, 2, 64);
        x += __shfl_xor(x, 4, 64);
        x += __shfl_xor(x, 8, 64);
        x += __shfl_xor(x, 16, 64);
        x += __shfl_xor(x, 32, 64);
        if (lane == 0) gpart[wv][h] = x;
    }
    __syncthreads();
    if (t < HH) gsum[t] = gpart[0][t] + gpart[1][t] + gpart[2][t] + gpart[3][t];
    __syncthreads();

    // ---- softmax + PV: wave wv handles h = wv and wv+4 ----
    const float* __restrict__ Vb = V + (size_t)b * NN * DD;
#pragma unroll
    for (int hh = 0; hh < 2; ++hh) {
        const int h = wv + hh * 4;
        float x[8];
#pragma unroll
        for (int k = 0; k < 8; ++k) x[k] = eb_lds[h][lane + (k << 6)];
        float mx = x[0];
#pragma unroll
        for (int k = 1; k < 8; ++k) mx = fmaxf(mx, x[k]);
        mx = fmaxf(mx, __shfl_xor(mx, 1, 64));
        mx = fmaxf(mx, __shfl_xor(mx, 2, 64));
        mx = fmaxf(mx, __shfl_xor(mx, 4, 64));
        mx = fmaxf(mx, __shfl_xor(mx, 8, 64));
        mx = fmaxf(mx, __shfl_xor(mx, 16, 64));
        mx = fmaxf(mx, __shfl_xor(mx, 32, 64));
        float p[8];
        float s = 0.f;
#pragma unroll
        for (int k = 0; k < 8; ++k) { p[k] = expf(x[k] - mx); s += p[k]; }
        s += __shfl_xor(s, 1, 64);
        s += __shfl_xor(s, 2, 64);
        s += __shfl_xor(s, 4, 64);
        s += __shfl_xor(s, 8, 64);
        s += __shfl_xor(s, 16, 64);
        s += __shfl_xor(s, 32, 64);

        float pv[8];
#pragma unroll
        for (int dk = 0; dk < 8; ++dk) pv[dk] = 0.f;
#pragma unroll
        for (int k = 0; k < 8; ++k) {
            const float* vr = Vb + (size_t)(lane + (k << 6)) * DD + h * DKK;
            const float4 va = *(const float4*)vr;
            const float4 vb2 = *(const float4*)(vr + 4);
            const float pk = p[k];
            pv[0] = fmaf(pk, va.x, pv[0]);
            pv[1] = fmaf(pk, va.y, pv[1]);
            pv[2] = fmaf(pk, va.z, pv[2]);
            pv[3] = fmaf(pk, va.w, pv[3]);
            pv[4] = fmaf(pk, vb2.x, pv[4]);
            pv[5] = fmaf(pk, vb2.y, pv[5]);
            pv[6] = fmaf(pk, vb2.z, pv[6]);
            pv[7] = fmaf(pk, vb2.w, pv[7]);
        }
#pragma unroll
        for (int dk = 0; dk < 8; ++dk) {
            float x2 = pv[dk];
            x2 += __shfl_xor(x2, 1, 64);
            x2 += __shfl_xor(x2, 2, 64);
            x2 += __shfl_xor(x2, 4, 64);
            x2 += __shfl_xor(x2, 8, 64);
            x2 += __shfl_xor(x2, 16, 64);
            x2 += __shfl_xor(x2, 32, 64);
            pv[dk] = x2;
        }
        if (lane == 0) {
            const float sc = log1pf(gsum[h]) / s;
#pragma unroll
            for (int dk = 0; dk < 8; ++dk) vh_lds[h * DKK + dk] = pv[dk] * sc;
        }
    }
    __syncthreads();

    // ---- n_out[b,i,:] = vh @ On ----
    if (t < DD) {
        const int j = t;
        float acc = 0.f;
#pragma unroll
        for (int d = 0; d < DD; ++d) acc = fmaf(vh_lds[d], On[d * DD + j], acc);
        n_out[(size_t)row * DD + j] = acc;
    }
}

extern "C" void kernel_launch(void* const* d_in, const int* in_sizes, int n_in,
                              void* d_out, int out_size, void* d_ws, size_t ws_size,
                              hipStream_t stream) {
    const float* n  = (const float*)d_in[0];
    const float* e  = (const float*)d_in[1];
    const float* Wq = (const float*)d_in[2];
    const float* Wk = (const float*)d_in[3];
    const float* Wv = (const float*)d_in[4];
    const float* On = (const float*)d_in[5];
    const float* We = (const float*)d_in[6];
    const float* Wg = (const float*)d_in[7];
    const float* Oe = (const float*)d_in[8];

    float* out = (float*)d_out;
    float* n_out = out;                                  // B*N*D floats
    float* e_out = out + (size_t)BB * NN * DD;           // B*N*N*D floats

    float* Q = (float*)d_ws;
    float* K = Q + (size_t)BB * NN * DD;
    float* V = K + (size_t)BB * NN * DD;

    qkv_kernel<<<BB * NN, 64, 0, stream>>>(n, Wq, Wk, Wv, Q, K, V);
    attn_kernel<<<BB * NN, 256, 0, stream>>>(e, Q, K, V, We, Wg, Oe, On, n_out, e_out);
}